// Round 9
// baseline (2166.606 us; speedup 1.0000x reference)
//
#include <hip/hip_runtime.h>
#include <math.h>

#define HD 128
#define NBR 8
#define LSTEPS 64
#define TILE_B 32
#define HT_PAD 36     // 144B rows: float4-aligned; GEMM h-reads are wave-uniform broadcasts
#define PART_PAD 68   // 68%32=4: mild 2-4 way on a tiny phase

// workspace layout (floats)
#define WPT_OFF   0        // w_hh repacked: [k][8*hh2+s], s<4 -> gate s,row hh2; s>=4 -> gate s-4,row hh2+64
#define WIPT_OFF  65536    // w_ih same repack                                            (128*512)
#define PP_OFF    131072   // P'' = w_emb@w_ih^T + bsum, same repack [j][8*hh2+s]         (8*512)
#define BSUM_OFF  135168   // (b_ih+b_hh) permuted [q*128+hh]                             (512)

__global__ __launch_bounds__(256) void setup_kernel(
    const float* __restrict__ w_emb, const float* __restrict__ w_ih,
    const float* __restrict__ w_hh, const float* __restrict__ b_ih,
    const float* __restrict__ b_hh, float* __restrict__ ws)
{
  int tid = blockIdx.x * blockDim.x + threadIdx.x;
  if (tid < 65536) {
    int k = tid >> 9, col = tid & 511;
    int hh2 = col >> 3, s = col & 7;
    int row = (s & 3) * HD + hh2 + 64 * (s >> 2);   // gate row in original [4H][H]
    ws[WPT_OFF + tid]  = w_hh[row * HD + k];
    ws[WIPT_OFF + tid] = w_ih[row * HD + k];
  }
  if (tid < 4096) {
    int j = tid >> 9, rem = tid & 511;
    int hh2 = rem >> 3, s = rem & 7;
    int row = (s & 3) * HD + hh2 + 64 * (s >> 2);
    const float* wr = w_ih + row * HD;
    const float* er = w_emb + j * HD;
    float sum = 0.f;
    for (int k = 0; k < HD; ++k) sum = fmaf(er[k], wr[k], sum);
    ws[PP_OFF + (size_t)j * 512 + rem] = sum + b_ih[row] + b_hh[row];
  }
  if (tid < 512) {
    int q = tid >> 7, hh = tid & 127;
    ws[BSUM_OFF + tid] = b_ih[q * HD + hh] + b_hh[q * HD + hh];
  }
}

__device__ __forceinline__ float fsig(float x) {
  return __fdividef(1.f, 1.f + __expf(-x));
}
__device__ __forceinline__ float ftanh(float x) {
  float ax = fabsf(x);
  float e  = __expf(-2.f * ax);
  float r  = __fdividef(1.f - e, 1.f + e);
  return copysignf(r, x);
}

// (8 gate-cols) x (8 batches) per thread: 64 explicit FMAs per k
#define ROW8(si, wv, H0, H1) \
  acc[si][0] = fmaf((H0).x, wv, acc[si][0]); acc[si][1] = fmaf((H0).y, wv, acc[si][1]); \
  acc[si][2] = fmaf((H0).z, wv, acc[si][2]); acc[si][3] = fmaf((H0).w, wv, acc[si][3]); \
  acc[si][4] = fmaf((H1).x, wv, acc[si][4]); acc[si][5] = fmaf((H1).y, wv, acc[si][5]); \
  acc[si][6] = fmaf((H1).z, wv, acc[si][6]); acc[si][7] = fmaf((H1).w, wv, acc[si][7]);

#define KFMA88(WA, WB, H0, H1) \
  ROW8(0, (WA).x, H0, H1) ROW8(1, (WA).y, H0, H1) ROW8(2, (WA).z, H0, H1) ROW8(3, (WA).w, H0, H1) \
  ROW8(4, (WB).x, H0, H1) ROW8(5, (WB).y, H0, H1) ROW8(6, (WB).z, H0, H1) ROW8(7, (WB).w, H0, H1)

// lgkm-only barrier: no vmcnt(0) drain (out-stores stay in flight)
#define BAR_LGKM() asm volatile("s_waitcnt lgkmcnt(0)\n\ts_barrier" ::: "memory")

__global__ __launch_bounds__(256, 2) void ctrl_kernel(
    const int* __restrict__ class_ids,
    const float* __restrict__ gumbel_u,
    const float* __restrict__ g_emb,
    const float* __restrict__ w_soft,
    const float* __restrict__ ws,
    float* __restrict__ out,
    int Btot)
{
  __shared__ __align__(16) float hT0[HD * HT_PAD];          // 18432 B
  __shared__ __align__(16) float hT1[HD * HT_PAD];          // 18432 B
  __shared__ __align__(16) float wsoft_l[NBR * HD];         // 4096 B
  __shared__ __align__(16) float part_l[TILE_B * PART_PAD]; // 8704 B
  __shared__ __align__(16) float pp_l[NBR * 512];           // 16384 B
  __shared__ int br_l[TILE_B];                              // 128 B  (~64.6 KB -> 2 blocks/CU)

  const int tid = threadIdx.x;
  const int b0  = blockIdx.x * TILE_B;
  const size_t BL = (size_t)Btot * LSTEPS;

  const float* __restrict__ wpT  = ws + WPT_OFF;
  const float* __restrict__ wipT = ws + WIPT_OFF;

  for (int i = tid; i < NBR*HD; i += 256) wsoft_l[i] = w_soft[i];
  for (int i = tid; i < NBR*512; i += 256) pp_l[i] = ws[PP_OFF + i];

  const int hh2 = tid & 63;   // hidden-pair index: owns rows hh2 and hh2+64
  const int bg  = tid >> 6;   // batch group 0..3 (8 batches each); wave-uniform
  const int slb = tid >> 3;   // sampling: batch owned by this 8-lane group (0..31)
  const int sr  = tid & 7;    // sampling: lane within group

  // ---- stage x0^T = g_emb[class_ids]^T into hT0 ----
  {
    int sb = tid >> 3;        // 0..31 batch
    int kc = tid & 7;         // k-chunk of 16
    int cid = class_ids[b0 + sb];
    const float* src = g_emb + (size_t)cid * HD + kc*16;
    #pragma unroll
    for (int ii = 0; ii < 4; ++ii) {
      float4 v = *(const float4*)(src + 4*ii);
      int kb = kc*16 + 4*ii;
      hT0[(kb+0)*HT_PAD + sb] = v.x;
      hT0[(kb+1)*HT_PAD + sb] = v.y;
      hT0[(kb+2)*HT_PAD + sb] = v.z;
      hT0[(kb+3)*HT_PAD + sb] = v.w;
    }
  }
  __syncthreads();

  // ---- q0 = 0.5*(x0 @ w_ih^T + bsum): 8 gate-cols x 8 batches, plain registers ----
  float q0[8][8];
  {
    float acc[8][8];
    #pragma unroll
    for (int s = 0; s < 8; ++s)
      #pragma unroll
      for (int j = 0; j < 8; ++j) acc[s][j] = 0.f;

    const float* wr = wipT + 8*hh2;
    const float* hr = hT0 + bg*8;
    #pragma unroll 2
    for (int k = 0; k < HD; ++k) {
      float4 wA = *(const float4*)(wr);
      float4 wB = *(const float4*)(wr + 4);
      float4 h0 = *(const float4*)(hr);
      float4 h1 = *(const float4*)(hr + 4);
      KFMA88(wA, wB, h0, h1);
      wr += 512; hr += HT_PAD;
    }
    #pragma unroll
    for (int s = 0; s < 8; ++s) {
      float bs = ws[BSUM_OFF + (s & 3)*HD + hh2 + 64*(s >> 2)];
      #pragma unroll
      for (int j = 0; j < 8; ++j)
        q0[s][j] = 0.5f * (acc[s][j] + bs);
    }
  }
  __syncthreads();

  float cA[8], cB[8];
  #pragma unroll
  for (int j = 0; j < 8; ++j) { cA[j] = 0.f; cB[j] = 0.f; }

  float* hcur = hT0;
  float* hnxt = hT1;

  for (int t = 0; t < LSTEPS; ++t) {
    // ---- gumbel load + transform, finalizer lanes only (overlaps GEMM) ----
    float gmb[8];
    if (sr == 0) {
      const float* up = gumbel_u + ((size_t)t * Btot + (b0 + slb)) * NBR;
      float4 ua = *(const float4*)up;
      float4 ub = *(const float4*)(up + 4);
      float uv[8] = {ua.x,ua.y,ua.z,ua.w,ub.x,ub.y,ub.z,ub.w};
      #pragma unroll
      for (int nb = 0; nb < 8; ++nb) {
        float uc = fminf(fmaxf(uv[nb], 1e-8f), 0.99999999f);
        gmb[nb] = -__logf(-__logf(uc));
      }
    }

    // ---- acc starts at q0; GEMM adds h @ w_hh^T ----
    float acc[8][8];
    #pragma unroll
    for (int s = 0; s < 8; ++s)
      #pragma unroll
      for (int j = 0; j < 8; ++j) acc[s][j] = q0[s][j];

    if (t > 0) {
      __builtin_amdgcn_s_setprio(1);
      const float* wr = wpT + 8*hh2;
      const float* hr = hcur + bg*8;
      // software pipeline: w 2-k deep (~280 cyc > L2 latency), h 1-k deep (> LDS latency)
      float4 wA0 = *(const float4*)(wr);
      float4 wB0 = *(const float4*)(wr + 4);
      float4 wA1 = *(const float4*)(wr + 512);
      float4 wB1 = *(const float4*)(wr + 516);
      float4 hA0 = *(const float4*)(hr);
      float4 hA1 = *(const float4*)(hr + 4);
      #pragma unroll 1
      for (int i = 0; i < 63; ++i) {
        float4 hB0 = *(const float4*)(hr + HT_PAD);
        float4 hB1 = *(const float4*)(hr + HT_PAD + 4);
        float4 wnA0 = *(const float4*)(wr + 2*512);
        float4 wnB0 = *(const float4*)(wr + 2*512 + 4);
        KFMA88(wA0, wB0, hA0, hA1);                       // k = 2i
        float4 hN0 = *(const float4*)(hr + 2*HT_PAD);
        float4 hN1 = *(const float4*)(hr + 2*HT_PAD + 4);
        float4 wnA1 = *(const float4*)(wr + 3*512);
        float4 wnB1 = *(const float4*)(wr + 3*512 + 4);
        KFMA88(wA1, wB1, hB0, hB1);                       // k = 2i+1
        wA0 = wnA0; wB0 = wnB0; wA1 = wnA1; wB1 = wnB1;
        hA0 = hN0; hA1 = hN1;
        wr += 1024; hr += 2*HT_PAD;
      }
      // epilogue: k = 126, 127 (no prefetch past the end)
      {
        float4 hB0 = *(const float4*)(hr + HT_PAD);
        float4 hB1 = *(const float4*)(hr + HT_PAD + 4);
        KFMA88(wA0, wB0, hA0, hA1);
        KFMA88(wA1, wB1, hB0, hB1);
      }
      __builtin_amdgcn_s_setprio(0);
    }

    // ---- combine x-part, LSTM pointwise: two hidden rows x 8 batches ----
    float h2A[8], h2B[8];
    #pragma unroll
    for (int j = 0; j < 8; ++j) {
      float g0,g1,g2,g3,g4,g5,g6,g7;
      if (t == 0) {
        g0 = 2.f*acc[0][j]; g1 = 2.f*acc[1][j]; g2 = 2.f*acc[2][j]; g3 = 2.f*acc[3][j];
        g4 = 2.f*acc[4][j]; g5 = 2.f*acc[5][j]; g6 = 2.f*acc[6][j]; g7 = 2.f*acc[7][j];
      } else {
        int br = br_l[bg*8 + j];
        float4 pA = *(const float4*)(&pp_l[br*512 + 8*hh2]);
        float4 pB = *(const float4*)(&pp_l[br*512 + 8*hh2 + 4]);
        g0 = fmaf(0.5f, pA.x, acc[0][j]);
        g1 = fmaf(0.5f, pA.y, acc[1][j]);
        g2 = fmaf(0.5f, pA.z, acc[2][j]);
        g3 = fmaf(0.5f, pA.w, acc[3][j]);
        g4 = fmaf(0.5f, pB.x, acc[4][j]);
        g5 = fmaf(0.5f, pB.y, acc[5][j]);
        g6 = fmaf(0.5f, pB.z, acc[6][j]);
        g7 = fmaf(0.5f, pB.w, acc[7][j]);
      }
      // row A (hidden hh2): gates i,f,g,o = g0..g3
      float ivA = fsig(g0), fvA = fsig(g1), gvA = ftanh(g2), ovA = fsig(g3);
      float c2A = fmaf(fvA, cA[j], ivA*gvA);
      cA[j] = c2A;
      h2A[j] = ovA * ftanh(c2A);
      // row B (hidden hh2+64): gates = g4..g7
      float ivB = fsig(g4), fvB = fsig(g5), gvB = ftanh(g6), ovB = fsig(g7);
      float c2B = fmaf(fvB, cB[j], ivB*gvB);
      cB[j] = c2B;
      h2B[j] = ovB * ftanh(c2B);
    }

    // write h_{t+1} into the other buffer (two rows; no pre-write barrier needed)
    {
      float* dA = &hnxt[hh2*HT_PAD + bg*8];
      *(float4*)(dA)   = make_float4(h2A[0],h2A[1],h2A[2],h2A[3]);
      *(float4*)(dA+4) = make_float4(h2A[4],h2A[5],h2A[6],h2A[7]);
      float* dB = &hnxt[(hh2+64)*HT_PAD + bg*8];
      *(float4*)(dB)   = make_float4(h2B[0],h2B[1],h2B[2],h2B[3]);
      *(float4*)(dB+4) = make_float4(h2B[4],h2B[5],h2B[6],h2B[7]);
    }
    BAR_LGKM();   // (B) new h visible (LDS only)

    // ---- logit partials: thread (lb = tid&31, ch = tid>>5 in 0..7), 16-k chunk each ----
    {
      int lb = tid & 31, ch = tid >> 5;
      const float* hp = hnxt + (ch*16)*HT_PAD + lb;
      float hv[16];
      #pragma unroll
      for (int i = 0; i < 16; ++i) hv[i] = hp[i*HT_PAD];
      #pragma unroll
      for (int nb = 0; nb < 8; ++nb) {
        const float4* wr2 = (const float4*)&wsoft_l[nb*HD + ch*16];
        float4 wa = wr2[0], wb = wr2[1], wc = wr2[2], wd = wr2[3];
        float p = 0.f;
        p = fmaf(hv[0],  wa.x, p); p = fmaf(hv[1],  wa.y, p);
        p = fmaf(hv[2],  wa.z, p); p = fmaf(hv[3],  wa.w, p);
        p = fmaf(hv[4],  wb.x, p); p = fmaf(hv[5],  wb.y, p);
        p = fmaf(hv[6],  wb.z, p); p = fmaf(hv[7],  wb.w, p);
        p = fmaf(hv[8],  wc.x, p); p = fmaf(hv[9],  wc.y, p);
        p = fmaf(hv[10], wc.z, p); p = fmaf(hv[11], wc.w, p);
        p = fmaf(hv[12], wd.x, p); p = fmaf(hv[13], wd.y, p);
        p = fmaf(hv[14], wd.z, p); p = fmaf(hv[15], wd.w, p);
        part_l[lb*PART_PAD + nb*8 + ch] = p;
      }
    }
    BAR_LGKM();   // (C) partials visible

    // ---- sampling: 8-lane group per batch, butterfly reduce, lane 0 finalizes ----
    {
      float s[8];
      #pragma unroll
      for (int nb = 0; nb < 8; ++nb)
        s[nb] = part_l[slb*PART_PAD + nb*8 + sr];
      #pragma unroll
      for (int mk = 1; mk < 8; mk <<= 1) {
        #pragma unroll
        for (int nb = 0; nb < 8; ++nb)
          s[nb] += __shfl_xor(s[nb], mk, 64);   // masks 1,2,4 stay within the 8-group
      }
      if (sr == 0) {
        float lg[8];
        #pragma unroll
        for (int nb = 0; nb < 8; ++nb)
          lg[nb] = 2.5f * ftanh(s[nb] * 0.2f);
        int br = 0; float best = lg[0] + gmb[0];
        #pragma unroll
        for (int nb = 1; nb < 8; ++nb) {
          float y = lg[nb] + gmb[nb];
          if (y > best) { best = y; br = nb; }   // strict > == first-occurrence argmax
        }
        br_l[slb] = br;
        float m = lg[0];
        #pragma unroll
        for (int nb = 1; nb < 8; ++nb) m = fmaxf(m, lg[nb]);
        float se = 0.f;
        #pragma unroll
        for (int nb = 0; nb < 8; ++nb) se += __expf(lg[nb] - m);
        float lse = __logf(se);
        float lp = (lg[br] - m) - lse;
        float ent = 0.f;
        #pragma unroll
        for (int nb = 0; nb < 8; ++nb) {
          float lpi = (lg[nb] - m) - lse;
          ent -= __expf(lpi) * lpi;
        }
        size_t row = (size_t)(b0 + slb) * LSTEPS + t;
        out[row]        = (float)br;
        out[BL + row]   = lp;
        out[2*BL + row] = ent;
        out[3*BL + row] = __expf(lp);
      }
    }
    BAR_LGKM();   // (E) br_l visible for next step's combine

    float* tmp = hcur; hcur = hnxt; hnxt = tmp;
  }
}

extern "C" void kernel_launch(void* const* d_in, const int* in_sizes, int n_in,
                              void* d_out, int out_size, void* d_ws, size_t ws_size,
                              hipStream_t stream) {
  const int*   class_ids = (const int*)d_in[0];
  const float* gumbel_u  = (const float*)d_in[1];
  const float* g_emb     = (const float*)d_in[2];
  const float* w_emb     = (const float*)d_in[3];
  const float* w_soft    = (const float*)d_in[4];
  const float* w_ih      = (const float*)d_in[5];
  const float* w_hh      = (const float*)d_in[6];
  const float* b_ih      = (const float*)d_in[7];
  const float* b_hh      = (const float*)d_in[8];
  float* out = (float*)d_out;
  float* ws  = (float*)d_ws;
  int B = in_sizes[0];

  hipLaunchKernelGGL(setup_kernel, dim3(256), dim3(256), 0, stream,
                     w_emb, w_ih, w_hh, b_ih, b_hh, ws);
  hipLaunchKernelGGL(ctrl_kernel, dim3(B / TILE_B), dim3(256), 0, stream,
                     class_ids, gumbel_u, g_emb, w_soft, ws, out, B);
}

// Round 11
// 1943.014 us; speedup vs baseline: 1.1151x; 1.1151x over previous
//
#include <hip/hip_runtime.h>
#include <math.h>

#define HD 128
#define NBR 8
#define LSTEPS 64
#define TILE_B 32
#define HT_PAD 36     // 144B rows: float4-aligned; GEMM h-reads are wave-uniform broadcasts
#define HRM_PAD 132   // row-major h rows: (132g+4i)%32 spreads groups across banks
#define WS_PAD 132    // wsoft rows padded: (132r+4i)%32 conflict-free across lanes

// workspace layout (floats)
#define WPT_OFF   0        // w_hh permuted-transposed: [k][4*hh+q] = w_hh[q*128+hh][k]   (128*512)
#define WIPT_OFF  65536    // w_ih same layout                                            (128*512)
#define PP_OFF    131072   // P'' = w_emb@w_ih^T + bsum, layout [j][4*hh+q]               (8*512)
#define BSUM_OFF  135168   // (b_ih+b_hh) permuted [q*128+hh]                             (512)

__global__ __launch_bounds__(256) void setup_kernel(
    const float* __restrict__ w_emb, const float* __restrict__ w_ih,
    const float* __restrict__ w_hh, const float* __restrict__ b_ih,
    const float* __restrict__ b_hh, float* __restrict__ ws)
{
  int tid = blockIdx.x * blockDim.x + threadIdx.x;
  if (tid < 65536) {
    int k = tid >> 9, col = tid & 511;
    int hh = col >> 2, q = col & 3;
    ws[WPT_OFF + tid]  = w_hh[(q*HD + hh)*HD + k];
    ws[WIPT_OFF + tid] = w_ih[(q*HD + hh)*HD + k];
  }
  if (tid < 4096) {
    int j = tid >> 9, rem = tid & 511;
    int q = rem >> 7, hh2 = rem & 127;
    const float* wr = w_ih + (q*HD + hh2)*HD;
    const float* er = w_emb + j*HD;
    float s = 0.f;
    for (int k = 0; k < HD; ++k) s = fmaf(er[k], wr[k], s);
    ws[PP_OFF + (size_t)j*512 + 4*hh2 + q] = s + b_ih[q*HD + hh2] + b_hh[q*HD + hh2];
  }
  if (tid < 512) {
    int q = tid >> 7, hh2 = tid & 127;
    ws[BSUM_OFF + tid] = b_ih[q*HD + hh2] + b_hh[q*HD + hh2];
  }
}

__device__ __forceinline__ float fsig(float x) {
  return __fdividef(1.f, 1.f + __expf(-x));
}
__device__ __forceinline__ float ftanh(float x) {
  float ax = fabsf(x);
  float e  = __expf(-2.f * ax);
  float r  = __fdividef(1.f - e, 1.f + e);
  return copysignf(r, x);
}

// 16 batches per thread: 64 explicit-component FMAs per k (named h vectors)
#define ROWQ16(qi, wq, H0, H1, H2, H3) \
  acc[qi][0]  = fmaf((H0).x, wq, acc[qi][0]);  acc[qi][1]  = fmaf((H0).y, wq, acc[qi][1]);  \
  acc[qi][2]  = fmaf((H0).z, wq, acc[qi][2]);  acc[qi][3]  = fmaf((H0).w, wq, acc[qi][3]);  \
  acc[qi][4]  = fmaf((H1).x, wq, acc[qi][4]);  acc[qi][5]  = fmaf((H1).y, wq, acc[qi][5]);  \
  acc[qi][6]  = fmaf((H1).z, wq, acc[qi][6]);  acc[qi][7]  = fmaf((H1).w, wq, acc[qi][7]);  \
  acc[qi][8]  = fmaf((H2).x, wq, acc[qi][8]);  acc[qi][9]  = fmaf((H2).y, wq, acc[qi][9]);  \
  acc[qi][10] = fmaf((H2).z, wq, acc[qi][10]); acc[qi][11] = fmaf((H2).w, wq, acc[qi][11]); \
  acc[qi][12] = fmaf((H3).x, wq, acc[qi][12]); acc[qi][13] = fmaf((H3).y, wq, acc[qi][13]); \
  acc[qi][14] = fmaf((H3).z, wq, acc[qi][14]); acc[qi][15] = fmaf((H3).w, wq, acc[qi][15]);

#define KFMA16(W, H0, H1, H2, H3) \
  ROWQ16(0, (W).x, H0, H1, H2, H3) ROWQ16(1, (W).y, H0, H1, H2, H3) \
  ROWQ16(2, (W).z, H0, H1, H2, H3) ROWQ16(3, (W).w, H0, H1, H2, H3)

// lgkm-only barrier: no vmcnt(0) drain (out-stores / w-prefetches stay in flight)
#define BAR_LGKM() asm volatile("s_waitcnt lgkmcnt(0)\n\ts_barrier" ::: "memory")

__global__ __launch_bounds__(256, 2) void ctrl_kernel(
    const int* __restrict__ class_ids,
    const float* __restrict__ gumbel_u,
    const float* __restrict__ g_emb,
    const float* __restrict__ w_soft,
    const float* __restrict__ ws,
    float* __restrict__ out,
    int Btot)
{
  __shared__ __align__(16) float hT[HD * HT_PAD];           // 18432 B (single buffer)
  __shared__ __align__(16) float h_rm[TILE_B * HRM_PAD];    // 16896 B (row-major h for sampling)
  __shared__ __align__(16) float wsoft_l[NBR * WS_PAD];     // 4224 B
  __shared__ __align__(16) float pp_l[NBR * 512];           // 16384 B
  __shared__ int br_l[TILE_B];                              // 128 B  (~56 KB -> 2 blocks/CU)

  const int tid = threadIdx.x;
  const int b0  = blockIdx.x * TILE_B;
  const size_t BL = (size_t)Btot * LSTEPS;

  const float* __restrict__ wpT  = ws + WPT_OFF;
  const float* __restrict__ wipT = ws + WIPT_OFF;

  // wsoft into padded LDS rows
  {
    int col = tid & 127, half = tid >> 7;
    #pragma unroll
    for (int rr = 0; rr < 4; ++rr)
      wsoft_l[(half*4 + rr)*WS_PAD + col] = w_soft[(half*4 + rr)*HD + col];
  }
  for (int i = tid; i < NBR*512; i += 256) pp_l[i] = ws[PP_OFF + i];

  const int hh = tid & 127;   // hidden/gate index (w cols 4*hh..4*hh+3)
  const int bg = tid >> 7;    // batch half: 0 -> batches 0..15, 1 -> 16..31
  const int sg = tid >> 3;    // sampling: batch group 0..31
  const int sr = tid & 7;     // sampling: branch nb owned by this lane

  // ---- stage x0^T = g_emb[class_ids]^T into hT ----
  {
    int sb = tid >> 3;        // 0..31 batch
    int kc = tid & 7;         // k-chunk of 16
    int cid = class_ids[b0 + sb];
    const float* src = g_emb + (size_t)cid * HD + kc*16;
    #pragma unroll
    for (int ii = 0; ii < 4; ++ii) {
      float4 v = *(const float4*)(src + 4*ii);
      int kb = kc*16 + 4*ii;
      hT[(kb+0)*HT_PAD + sb] = v.x;
      hT[(kb+1)*HT_PAD + sb] = v.y;
      hT[(kb+2)*HT_PAD + sb] = v.z;
      hT[(kb+3)*HT_PAD + sb] = v.w;
    }
  }
  __syncthreads();

  // ---- q0 = 0.5*(x0 @ w_ih^T + bsum) for 16 batches, plain registers ----
  float q0[4][16];
  {
    float acc[4][16];
    #pragma unroll
    for (int q = 0; q < 4; ++q)
      #pragma unroll
      for (int j = 0; j < 16; ++j) acc[q][j] = 0.f;

    const float* wr = wipT + 4*hh;
    const float* hr = hT + bg*16;
    #pragma unroll 2
    for (int k = 0; k < HD; ++k) {
      float4 w  = *(const float4*)(wr);
      float4 h0 = *(const float4*)(hr);
      float4 h1 = *(const float4*)(hr + 4);
      float4 h2 = *(const float4*)(hr + 8);
      float4 h3 = *(const float4*)(hr + 12);
      KFMA16(w, h0, h1, h2, h3);
      wr += 512; hr += HT_PAD;
    }
    #pragma unroll
    for (int q = 0; q < 4; ++q) {
      float bs = ws[BSUM_OFF + q*HD + hh];
      #pragma unroll
      for (int j = 0; j < 16; ++j)
        q0[q][j] = 0.5f * (acc[q][j] + bs);
    }
  }
  __syncthreads();

  float c[16];
  #pragma unroll
  for (int j = 0; j < 16; ++j) c[j] = 0.f;

  for (int t = 0; t < LSTEPS; ++t) {
    // ---- gumbel: 1 coalesced dword per lane (u for batch sg, branch sr); hidden under GEMM ----
    float uval = gumbel_u[((size_t)t * Btot + b0) * NBR + tid];

    // ---- acc starts at q0 (x0-part + bias pre-folded); GEMM adds h @ w_hh^T ----
    float acc[4][16];
    #pragma unroll
    for (int q = 0; q < 4; ++q)
      #pragma unroll
      for (int j = 0; j < 16; ++j) acc[q][j] = q0[q][j];

    if (t > 0) {
      __builtin_amdgcn_s_setprio(1);
      const float* wr = wpT + 4*hh;
      const float* hr = hT + bg*16;
      // software pipeline: w 2-k deep (~280 cyc > L2 latency), h 1-k deep (> LDS latency)
      float4 w0 = *(const float4*)(wr);
      float4 w1 = *(const float4*)(wr + 512);
      float4 hA0 = *(const float4*)(hr);
      float4 hA1 = *(const float4*)(hr + 4);
      float4 hA2 = *(const float4*)(hr + 8);
      float4 hA3 = *(const float4*)(hr + 12);
      #pragma unroll 1
      for (int i = 0; i < 63; ++i) {
        float4 hB0 = *(const float4*)(hr + HT_PAD);
        float4 hB1 = *(const float4*)(hr + HT_PAD + 4);
        float4 hB2 = *(const float4*)(hr + HT_PAD + 8);
        float4 hB3 = *(const float4*)(hr + HT_PAD + 12);
        float4 wn0 = *(const float4*)(wr + 2*512);
        float4 wc0 = w0;
        KFMA16(wc0, hA0, hA1, hA2, hA3);                  // k = 2i
        float4 hN0 = *(const float4*)(hr + 2*HT_PAD);
        float4 hN1 = *(const float4*)(hr + 2*HT_PAD + 4);
        float4 hN2 = *(const float4*)(hr + 2*HT_PAD + 8);
        float4 hN3 = *(const float4*)(hr + 2*HT_PAD + 12);
        float4 wn1 = *(const float4*)(wr + 3*512);
        float4 wc1 = w1;
        KFMA16(wc1, hB0, hB1, hB2, hB3);                  // k = 2i+1
        w0 = wn0; w1 = wn1;
        hA0 = hN0; hA1 = hN1; hA2 = hN2; hA3 = hN3;
        wr += 1024; hr += 2*HT_PAD;
      }
      // epilogue: k = 126, 127 (no prefetch past the end)
      {
        float4 hB0 = *(const float4*)(hr + HT_PAD);
        float4 hB1 = *(const float4*)(hr + HT_PAD + 4);
        float4 hB2 = *(const float4*)(hr + HT_PAD + 8);
        float4 hB3 = *(const float4*)(hr + HT_PAD + 12);
        KFMA16(w0, hA0, hA1, hA2, hA3);
        KFMA16(w1, hB0, hB1, hB2, hB3);
      }
      __builtin_amdgcn_s_setprio(0);
    }

    // (E) br_l(t-1) visible for combine; also: every wave's hT/h_rm reads of the
    // previous step are complete (they happened before this wave's GEMM), so the
    // writes below are race-free with a SINGLE hT buffer.
    BAR_LGKM();

    // ---- combine x-part, LSTM pointwise ----
    float h2v[16];
    #pragma unroll
    for (int j = 0; j < 16; ++j) {
      float gi, gf, gg, go;
      if (t == 0) {
        gi = 2.f*acc[0][j]; gf = 2.f*acc[1][j];
        gg = 2.f*acc[2][j]; go = 2.f*acc[3][j];
      } else {
        int br = br_l[bg*16 + j];
        float4 pv = *(const float4*)(&pp_l[br*512 + 4*hh]);
        gi = fmaf(0.5f, pv.x, acc[0][j]);
        gf = fmaf(0.5f, pv.y, acc[1][j]);
        gg = fmaf(0.5f, pv.z, acc[2][j]);
        go = fmaf(0.5f, pv.w, acc[3][j]);
      }
      float iv = fsig(gi);
      float fv = fsig(gf);
      float gv = ftanh(gg);
      float ov = fsig(go);
      float c2 = fmaf(fv, c[j], iv*gv);
      c[j] = c2;
      h2v[j] = ov * ftanh(c2);
    }

    // write h_{t+1}: transposed (for next GEMM) + row-major (for sampling)
    {
      float* dst = &hT[hh*HT_PAD + bg*16];
      *(float4*)(dst)    = make_float4(h2v[0], h2v[1], h2v[2], h2v[3]);
      *(float4*)(dst+4)  = make_float4(h2v[4], h2v[5], h2v[6], h2v[7]);
      *(float4*)(dst+8)  = make_float4(h2v[8], h2v[9], h2v[10],h2v[11]);
      *(float4*)(dst+12) = make_float4(h2v[12],h2v[13],h2v[14],h2v[15]);
      #pragma unroll
      for (int j = 0; j < 16; ++j)
        h_rm[(bg*16 + j)*HRM_PAD + hh] = h2v[j];
    }
    BAR_LGKM();   // (B) new h visible

    // ---- sampling: lane (sg, sr) owns branch sr of batch sg; fully in-lane dot ----
    {
      const float* hp  = h_rm + sg*HRM_PAD;      // broadcast across the 8 lanes of the group
      const float* wp2 = wsoft_l + sr*WS_PAD;    // conflict-free (132-pad)
      float p = 0.f;
      #pragma unroll
      for (int i = 0; i < 32; ++i) {
        float4 hv = *(const float4*)(hp + 4*i);
        float4 wv = *(const float4*)(wp2 + 4*i);
        p = fmaf(hv.x, wv.x, p); p = fmaf(hv.y, wv.y, p);
        p = fmaf(hv.z, wv.z, p); p = fmaf(hv.w, wv.w, p);
      }
      float lg = 2.5f * ftanh(p * 0.2f);
      float uc = fminf(fmaxf(uval, 1e-8f), 0.99999999f);
      float y  = lg - __logf(-__logf(uc));
      // argmax over the 8 lanes, first-occurrence tie-break (y desc, nb asc)
      int   bi = sr;
      float by = y;
      #pragma unroll
      for (int mk = 1; mk < 8; mk <<= 1) {
        float oy = __shfl_xor(by, mk, 64);
        int   ob = __shfl_xor(bi, mk, 64);
        if (oy > by || (oy == by && ob < bi)) { by = oy; bi = ob; }
      }
      // softmax stats across the 8 lanes
      float m = lg;
      #pragma unroll
      for (int mk = 1; mk < 8; mk <<= 1) m = fmaxf(m, __shfl_xor(m, mk, 64));
      float se = __expf(lg - m);
      #pragma unroll
      for (int mk = 1; mk < 8; mk <<= 1) se += __shfl_xor(se, mk, 64);
      float lse = __logf(se);
      float lpi = (lg - m) - lse;
      float ent = __expf(lpi) * lpi;
      #pragma unroll
      for (int mk = 1; mk < 8; mk <<= 1) ent += __shfl_xor(ent, mk, 64);
      ent = -ent;
      float lgbr = __shfl(lg, (tid & 56) + bi, 64);   // winner lane's logit
      float lp = (lgbr - m) - lse;
      if (sr == 0) {
        br_l[sg] = bi;
        size_t row = (size_t)(b0 + sg) * LSTEPS + t;
        out[row]        = (float)bi;
        out[BL + row]   = lp;
        out[2*BL + row] = ent;
        out[3*BL + row] = __expf(lp);
      }
    }
    // no barrier here: the next iteration's (E) barrier (after GEMM) orders
    // br_l writes before combine's reads, and h_rm reads before its overwrite.
  }
}

extern "C" void kernel_launch(void* const* d_in, const int* in_sizes, int n_in,
                              void* d_out, int out_size, void* d_ws, size_t ws_size,
                              hipStream_t stream) {
  const int*   class_ids = (const int*)d_in[0];
  const float* gumbel_u  = (const float*)d_in[1];
  const float* g_emb     = (const float*)d_in[2];
  const float* w_emb     = (const float*)d_in[3];
  const float* w_soft    = (const float*)d_in[4];
  const float* w_ih      = (const float*)d_in[5];
  const float* w_hh      = (const float*)d_in[6];
  const float* b_ih      = (const float*)d_in[7];
  const float* b_hh      = (const float*)d_in[8];
  float* out = (float*)d_out;
  float* ws  = (float*)d_ws;
  int B = in_sizes[0];

  hipLaunchKernelGGL(setup_kernel, dim3(256), dim3(256), 0, stream,
                     w_emb, w_ih, w_hh, b_ih, b_hh, ws);
  hipLaunchKernelGGL(ctrl_kernel, dim3(B / TILE_B), dim3(256), 0, stream,
                     class_ids, gumbel_u, g_emb, w_soft, ws, out, B);
}